// Round 16
// baseline (560.693 us; speedup 1.0000x reference)
//
#include <hip/hip_runtime.h>

#define BB 16
#define SS 1024
#define TT 512
#define DD 256
#define HH 8
#define LL 4
#define FFN 1024
#define DHH 32
#define MROWS (BB*SS)   // 16384

typedef short bf16x8 __attribute__((ext_vector_type(8)));
typedef float f32x4 __attribute__((ext_vector_type(4)));
typedef float f32x2 __attribute__((ext_vector_type(2)));
typedef unsigned int u32x4 __attribute__((ext_vector_type(4)));

__device__ __forceinline__ unsigned short f2bf(float f) {
    unsigned int u = __float_as_uint(f);
    unsigned int r = (u + 0x7fffu + ((u >> 16) & 1u)) >> 16;
    return (unsigned short)r;
}
__device__ __forceinline__ float bf2f(unsigned short h) {
    return __uint_as_float(((unsigned int)h) << 16);
}
__device__ __forceinline__ unsigned int packbf(float a, float b) {
    return (__float_as_uint(a) >> 16) | (__float_as_uint(b) & 0xffff0000u);
}
// one v_perm_b32: low16 = bf16trunc(p0), high16 = bf16trunc(p1)
__device__ __forceinline__ unsigned int packbf_perm(float p0, float p1) {
    return __builtin_amdgcn_perm(__float_as_uint(p1), __float_as_uint(p0), 0x07060302u);
}

// async global->LDS, 16B per lane. LDS dest must be wave-uniform base + lane*16.
__device__ __forceinline__ void g2l16(const unsigned short* g, unsigned short* l) {
    __builtin_amdgcn_global_load_lds(
        (const __attribute__((address_space(1))) unsigned int*)g,
        (__attribute__((address_space(3))) unsigned int*)l, 16, 0, 0);
}

// ---------------- weight conversion (fp32 -> bf16) ----------------
__global__ __launch_bounds__(256) void convert_weights(
    const float* __restrict__ w0, const float* __restrict__ w1, const float* __restrict__ w2,
    const float* __restrict__ w3, const float* __restrict__ w4, unsigned short* __restrict__ dst)
{
    int i = blockIdx.x * 256 + threadIdx.x;
    if (i >= 3276800) return;
    float v;
    if (i < 131072)        v = w0[i];
    else if (i < 917504)   v = w1[i - 131072];
    else if (i < 1179648)  v = w2[i - 917504];
    else if (i < 2228224)  v = w3[i - 1179648];
    else                   v = w4[i - 2228224];
    dst[i] = f2bf(v);
}

__global__ __launch_bounds__(256) void convert_x(const float4* __restrict__ x, ushort4* __restrict__ xb, int n4)
{
    int i = blockIdx.x * 256 + threadIdx.x;
    if (i >= n4) return;
    float4 v = x[i];
    ushort4 o;
    o.x = f2bf(v.x); o.y = f2bf(v.y); o.z = f2bf(v.z); o.w = f2bf(v.w);
    xb[i] = o;
}

// ---------------- wide GEMM (lin1): 128 x BN block, BK=32, permuted-B wide epilogue ----------------
template<int BN, int RELU>
__global__ __launch_bounds__(256, 2) void gemm_lds(
    const unsigned short* __restrict__ A, const unsigned short* __restrict__ Bw,
    const float* __restrict__ bias, void* out, int M, int N, int K)
{
    constexpr int NJ = BN / 32;
    __shared__ __align__(16) unsigned short sA[2][128 * 32];
    __shared__ __align__(16) unsigned short sB[2][BN * 32];
    const int t = threadIdx.x;
    const int lane = t & 63, quad = lane >> 4, l16 = lane & 15;
    const int wave = t >> 6, wm = wave >> 1, wn = wave & 1;
    const int row0 = blockIdx.y * 128, col0 = blockIdx.x * BN;

    const unsigned short* gA = A + (size_t)(row0 + (t >> 2)) * K + (t & 3) * 8;
    const size_t rstep = (size_t)64 * K;
    const unsigned short* gBp[BN / 64];
    #pragma unroll
    for (int p = 0; p < BN / 64; ++p) {
        int l = p * 64 + (t >> 2);
        int wrow = (l & (16 * NJ)) + (l & 15) * NJ + ((l >> 4) & (NJ - 1));
        gBp[p] = Bw + (size_t)(col0 + wrow) * K + (t & 3) * 8;
    }

    f32x4 acc[4][NJ];
    #pragma unroll
    for (int i = 0; i < 4; ++i)
        #pragma unroll
        for (int j = 0; j < NJ; ++j)
            acc[i][j] = (f32x4){0.f, 0.f, 0.f, 0.f};

    g2l16(gA, &sA[0][t * 8]);
    g2l16(gA + rstep, &sA[0][(t + 256) * 8]);
    #pragma unroll
    for (int p = 0; p < BN / 64; ++p)
        g2l16(gBp[p], &sB[0][p * 2048 + t * 8]);

    for (int k0 = 0; k0 < K; k0 += 32) {
        const int cur = (k0 >> 5) & 1;
        __syncthreads();
        if (k0 + 32 < K) {
            const int nxt = cur ^ 1;
            g2l16(gA + k0 + 32, &sA[nxt][t * 8]);
            g2l16(gA + rstep + k0 + 32, &sA[nxt][(t + 256) * 8]);
            #pragma unroll
            for (int p = 0; p < BN / 64; ++p)
                g2l16(gBp[p] + k0 + 32, &sB[nxt][p * 2048 + t * 8]);
        }
        bf16x8 a[4], b[NJ];
        #pragma unroll
        for (int i = 0; i < 4; ++i)
            a[i] = *(const bf16x8*)(&sA[cur][(wm * 64 + i * 16 + l16) * 32 + quad * 8]);
        #pragma unroll
        for (int j = 0; j < NJ; ++j)
            b[j] = *(const bf16x8*)(&sB[cur][(wn * (BN / 2) + j * 16 + l16) * 32 + quad * 8]);
        #pragma unroll
        for (int i = 0; i < 4; ++i)
            #pragma unroll
            for (int j = 0; j < NJ; ++j)
                acc[i][j] = __builtin_amdgcn_mfma_f32_16x16x32_bf16(a[i], b[j], acc[i][j], 0, 0, 0);
    }

    const int colbase = col0 + wn * (BN / 2) + l16 * NJ;
    float bb[NJ];
    #pragma unroll
    for (int j = 0; j < NJ; ++j) bb[j] = bias[colbase + j];
    #pragma unroll
    for (int i = 0; i < 4; ++i) {
        #pragma unroll
        for (int r = 0; r < 4; ++r) {
            int row = row0 + wm * 64 + i * 16 + quad * 4 + r;
            float v[NJ];
            #pragma unroll
            for (int j = 0; j < NJ; ++j) {
                v[j] = acc[i][j][r] + bb[j];
                if (RELU) v[j] = fmaxf(v[j], 0.f);
            }
            unsigned short* dst = (unsigned short*)out + (size_t)row * N + colbase;
            if constexpr (NJ == 4) {
                uint2 w; w.x = packbf(v[0], v[1]); w.y = packbf(v[2], v[3]);
                *(uint2*)dst = w;
            } else {
                uint4 w; w.x = packbf(v[0], v[1]); w.y = packbf(v[2], v[3]);
                w.z = packbf(v[4], v[5]); w.w = packbf(v[6], v[7]);
                *(uint4*)dst = w;
            }
        }
    }
}

// ---------------- qkv GEMM with fused RoPE + layout epilogue ----------------
// (unchanged from round 9 -- writes qr/kr/vt directly, no rope dispatch)
__global__ __launch_bounds__(256, 2) void gemm_qkv(
    const unsigned short* __restrict__ A, const unsigned short* __restrict__ Bw,
    const float* __restrict__ bias,
    unsigned short* __restrict__ qr, unsigned short* __restrict__ kr,
    unsigned short* __restrict__ vt)
{
    constexpr int K = 256;
    __shared__ __align__(16) unsigned short sA[2][128 * 32];   // 16 KB
    __shared__ __align__(16) unsigned short sB[2][128 * 32];   // 16 KB
    __shared__ float scc[128 * 20], scs[128 * 20];             // 20 KB sincos (stride-20 pad)
    const int t = threadIdx.x;
    const int lane = t & 63, quad = lane >> 4, l16 = lane & 15;
    const int wave = t >> 6, wm = wave >> 1, wn = wave & 1;
    const int row0 = blockIdx.y * 128, col0 = blockIdx.x * 128;
    const int sec = blockIdx.x >> 1;                           // 0=Q 1=K 2=V
    const int b = row0 >> 10, s0 = row0 & 1023;

    if (sec < 2) {
        #pragma unroll
        for (int k = 0; k < 8; ++k) {
            int e = t * 8 + k;                                 // 2048 entries
            int rl = e >> 4, jj = e & 15;
            float ivf = __expf(-(float)jj * 0.575646273248511f);  // 10000^(-jj/16)
            float c, sn;
            __sincosf((float)(s0 + rl) * ivf, &sn, &c);
            scc[rl * 20 + jj] = c;
            scs[rl * 20 + jj] = sn;
        }
    }

    const unsigned short* gA = A + (size_t)(row0 + (t >> 2)) * K + (t & 3) * 8;
    const size_t rstep = (size_t)64 * K;
    const unsigned short* gBp[2];
    #pragma unroll
    for (int p = 0; p < 2; ++p) {
        int l = p * 64 + (t >> 2);
        int wrow = (l & 64) + (l & 15) * 4 + ((l >> 4) & 3);
        gBp[p] = Bw + (size_t)(col0 + wrow) * K + (t & 3) * 8;
    }

    f32x4 acc[4][4];
    #pragma unroll
    for (int i = 0; i < 4; ++i)
        #pragma unroll
        for (int j = 0; j < 4; ++j)
            acc[i][j] = (f32x4){0.f, 0.f, 0.f, 0.f};

    g2l16(gA, &sA[0][t * 8]);
    g2l16(gA + rstep, &sA[0][(t + 256) * 8]);
    #pragma unroll
    for (int p = 0; p < 2; ++p)
        g2l16(gBp[p], &sB[0][p * 2048 + t * 8]);

    for (int k0 = 0; k0 < K; k0 += 32) {
        const int cur = (k0 >> 5) & 1;
        __syncthreads();
        if (k0 + 32 < K) {
            const int nxt = cur ^ 1;
            g2l16(gA + k0 + 32, &sA[nxt][t * 8]);
            g2l16(gA + rstep + k0 + 32, &sA[nxt][(t + 256) * 8]);
            #pragma unroll
            for (int p = 0; p < 2; ++p)
                g2l16(gBp[p] + k0 + 32, &sB[nxt][p * 2048 + t * 8]);
        }
        bf16x8 a[4], bfr[4];
        #pragma unroll
        for (int i = 0; i < 4; ++i)
            a[i] = *(const bf16x8*)(&sA[cur][(wm * 64 + i * 16 + l16) * 32 + quad * 8]);
        #pragma unroll
        for (int j = 0; j < 4; ++j)
            bfr[j] = *(const bf16x8*)(&sB[cur][(wn * 64 + j * 16 + l16) * 32 + quad * 8]);
        #pragma unroll
        for (int i = 0; i < 4; ++i)
            #pragma unroll
            for (int j = 0; j < 4; ++j)
                acc[i][j] = __builtin_amdgcn_mfma_f32_16x16x32_bf16(a[i], bfr[j], acc[i][j], 0, 0, 0);
    }

    // ---- fused RoPE/layout epilogue ----
    const int gcol = col0 + wn * 64 + l16 * 4;     // global qkv column
    const int cc = gcol & 255;                     // column within section
    const int h = cc >> 5, d0v = cc & 31, j0 = d0v & 15;
    const int bh = (b << 3) | h;
    float bbv[4];
    *(float4*)bbv = *(const float4*)(bias + gcol);

    if (sec < 2) {
        const float sgn = ((l16 & 4) == 0) ? -1.f : 1.f;   // d<16 -> -partner
        const float qs = 1.4426950408889634f / 5.656854249492381f;  // log2e/sqrt(32)
        #pragma unroll
        for (int i = 0; i < 4; ++i) {
            #pragma unroll
            for (int r = 0; r < 4; ++r) {
                const int rl = wm * 64 + i * 16 + quad * 4 + r;
                float v0 = acc[i][0][r] + bbv[0];
                float v1 = acc[i][1][r] + bbv[1];
                float v2 = acc[i][2][r] + bbv[2];
                float v3 = acc[i][3][r] + bbv[3];
                float p0 = __shfl_xor(v0, 4);
                float p1 = __shfl_xor(v1, 4);
                float p2 = __shfl_xor(v2, 4);
                float p3 = __shfl_xor(v3, 4);
                float4 cv = *(const float4*)(&scc[rl * 20 + j0]);
                float4 sv = *(const float4*)(&scs[rl * 20 + j0]);
                float o0 = v0 * cv.x + sgn * p0 * sv.x;
                float o1 = v1 * cv.y + sgn * p1 * sv.y;
                float o2 = v2 * cv.z + sgn * p2 * sv.z;
                float o3 = v3 * cv.w + sgn * p3 * sv.w;
                const int s = s0 + rl;
                uint2 w;
                if (sec == 0) {
                    o0 *= qs; o1 *= qs; o2 *= qs; o3 *= qs;
                    w.x = packbf(o0, o1); w.y = packbf(o2, o3);
                    *(uint2*)(qr + ((size_t)bh * SS + s) * DHH + d0v) = w;
                } else {
                    int jj2 = s & 31;
                    int sp = (s & ~31) | (((jj2 & 1) << 4) | (jj2 >> 1));  // even/odd interleave
                    w.x = packbf(o0, o1); w.y = packbf(o2, o3);
                    *(uint2*)(kr + ((size_t)bh * SS + sp) * DHH + d0v) = w;
                }
            }
        }
    } else {
        #pragma unroll
        for (int i = 0; i < 4; ++i) {
            const int sbase = s0 + wm * 64 + i * 16 + quad * 4;
            #pragma unroll
            for (int j = 0; j < 4; ++j) {
                float w0 = acc[i][j][0] + bbv[j];
                float w1 = acc[i][j][1] + bbv[j];
                float w2 = acc[i][j][2] + bbv[j];
                float w3 = acc[i][j][3] + bbv[j];
                uint2 w; w.x = packbf(w0, w1); w.y = packbf(w2, w3);
                *(uint2*)(vt + ((size_t)bh * DHH + d0v + j) * SS + sbase) = w;
            }
        }
    }
}

// ---------------- full-row GEMM (tokenize / out-proj / lin2): 32 x 256 block,
// BK=64 via QUARTER-PAIR staging (kept: measured ~25us aggregate gain r14/r15).
// One barrier per 64-K; conflict-free 32-half-row LDS layout. Fused bias+resid+row-LN.
template<int RESID, int LNH, int YF32>
__global__ __launch_bounds__(256, 2) void gemm_row(
    const unsigned short* __restrict__ A, const unsigned short* __restrict__ Bw,
    const float* __restrict__ bias, const float* __restrict__ resid,
    float* __restrict__ hout, void* __restrict__ yout,
    const float* __restrict__ gh, const float* __restrict__ bh,
    const float* __restrict__ gy, const float* __restrict__ by, int K)
{
    __shared__ __align__(16) unsigned short sA[4][32 * 32];    //  8 KB (4 k-quarters)
    __shared__ __align__(16) unsigned short sB[4][256 * 32];   // 64 KB
    __shared__ float2 part[2][32][4];                          //  1 KB row partials
    const int t = threadIdx.x;
    const int quad = (t >> 4) & 3, l16 = t & 15;
    const int wn = t >> 6;                                     // 4 col-waves
    const int row0 = blockIdx.x * 32;

    const int tq = t & 127, aq = t >> 7;   // A staging: waves 0-1 -> quarter lo, 2-3 -> hi
    const unsigned short* gA = A + (size_t)(row0 + (tq >> 2)) * K + (tq & 3) * 8;
    const unsigned short* gB[4];
    #pragma unroll
    for (int p = 0; p < 4; ++p) {
        int l = p * 64 + (t >> 2);
        gB[p] = Bw + (size_t)((l & 192) + (l & 15) * 4 + ((l >> 4) & 3)) * K + (t & 3) * 8;
    }

    f32x4 acc[2][4];
    #pragma unroll
    for (int i = 0; i < 2; ++i)
        #pragma unroll
        for (int j = 0; j < 4; ++j)
            acc[i][j] = (f32x4){0.f, 0.f, 0.f, 0.f};

    // stage a PAIR of 32-k quarters (64 K) into quarters 2p / 2p+1
    auto stage = [&](int k0, int p) {
        g2l16(gA + k0 + aq * 32, &sA[2 * p + aq][tq * 8]);
        #pragma unroll
        for (int i = 0; i < 4; ++i) {
            g2l16(gB[i] + k0,      &sB[2 * p][i * 2048 + t * 8]);
            g2l16(gB[i] + k0 + 32, &sB[2 * p + 1][i * 2048 + t * 8]);
        }
    };

    stage(0, 0);
    for (int k0 = 0; k0 < K; k0 += 64) {
        const int cur = (k0 >> 6) & 1;
        __syncthreads();
        if (k0 + 64 < K) stage(k0 + 64, cur ^ 1);
        #pragma unroll
        for (int kh = 0; kh < 2; ++kh) {
            bf16x8 a[2], b[4];
            #pragma unroll
            for (int i = 0; i < 2; ++i)
                a[i] = *(const bf16x8*)(&sA[2 * cur + kh][(i * 16 + l16) * 32 + quad * 8]);
            #pragma unroll
            for (int j = 0; j < 4; ++j)
                b[j] = *(const bf16x8*)(&sB[2 * cur + kh][(wn * 64 + j * 16 + l16) * 32 + quad * 8]);
            #pragma unroll
            for (int i = 0; i < 2; ++i)
                #pragma unroll
                for (int j = 0; j < 4; ++j)
                    acc[i][j] = __builtin_amdgcn_mfma_f32_16x16x32_bf16(a[i], b[j], acc[i][j], 0, 0, 0);
        }
    }

    // ---- epilogue: bias + resid, row stats (stage 1) ----
    const int colbase = wn * 64 + l16 * 4;
    const float4 bb = *(const float4*)(bias + colbase);
    #pragma unroll
    for (int i = 0; i < 2; ++i) {
        #pragma unroll
        for (int r = 0; r < 4; ++r) {
            const int rl = i * 16 + quad * 4 + r;
            float v0 = acc[i][0][r] + bb.x;
            float v1 = acc[i][1][r] + bb.y;
            float v2 = acc[i][2][r] + bb.z;
            float v3 = acc[i][3][r] + bb.w;
            if (RESID) {
                float4 rv = *(const float4*)(resid + (size_t)(row0 + rl) * DD + colbase);
                v0 += rv.x; v1 += rv.y; v2 += rv.z; v3 += rv.w;
            }
            acc[i][0][r] = v0; acc[i][1][r] = v1; acc[i][2][r] = v2; acc[i][3][r] = v3;
            float s = v0 + v1 + v2 + v3;
            float ss = v0 * v0 + v1 * v1 + v2 * v2 + v3 * v3;
            #pragma unroll
            for (int m = 1; m <= 8; m <<= 1) { s += __shfl_xor(s, m); ss += __shfl_xor(ss, m); }
            if (l16 == 0) part[0][rl][wn] = (float2){s, ss};
        }
    }
    __syncthreads();

    float4 gyv = *(const float4*)(gy + colbase);
    float4 byv = *(const float4*)(by + colbase);
    float4 ghv = {0.f, 0.f, 0.f, 0.f}, bhv = {0.f, 0.f, 0.f, 0.f};
    if (LNH) { ghv = *(const float4*)(gh + colbase); bhv = *(const float4*)(bh + colbase); }

    // ---- stage 2: LN from stats; write h; (LNH: restage stats of h) ----
    #pragma unroll
    for (int i = 0; i < 2; ++i) {
        #pragma unroll
        for (int r = 0; r < 4; ++r) {
            const int rl = i * 16 + quad * 4 + r;
            float2 p0 = part[0][rl][0], p1 = part[0][rl][1], p2 = part[0][rl][2], p3 = part[0][rl][3];
            float mean = (p0.x + p1.x + p2.x + p3.x) * (1.f / 256.f);
            float var  = (p0.y + p1.y + p2.y + p3.y) * (1.f / 256.f) - mean * mean;
            float inv  = rsqrtf(var + 1e-5f);
            float h0, h1, h2, h3;
            if (LNH) {
                h0 = (acc[i][0][r] - mean) * inv * ghv.x + bhv.x;
                h1 = (acc[i][1][r] - mean) * inv * ghv.y + bhv.y;
                h2 = (acc[i][2][r] - mean) * inv * ghv.z + bhv.z;
                h3 = (acc[i][3][r] - mean) * inv * ghv.w + bhv.w;
            } else {
                h0 = acc[i][0][r]; h1 = acc[i][1][r]; h2 = acc[i][2][r]; h3 = acc[i][3][r];
            }
            if (!YF32)
                *(float4*)(hout + (size_t)(row0 + rl) * DD + colbase) = (float4){h0, h1, h2, h3};
            if (LNH) {
                acc[i][0][r] = h0; acc[i][1][r] = h1; acc[i][2][r] = h2; acc[i][3][r] = h3;
                float s = h0 + h1 + h2 + h3;
                float ss = h0 * h0 + h1 * h1 + h2 * h2 + h3 * h3;
                #pragma unroll
                for (int m = 1; m <= 8; m <<= 1) { s += __shfl_xor(s, m); ss += __shfl_xor(ss, m); }
                if (l16 == 0) part[1][rl][wn] = (float2){s, ss};
            } else {
                float y0 = (h0 - mean) * inv * gyv.x + byv.x;
                float y1 = (h1 - mean) * inv * gyv.y + byv.y;
                float y2 = (h2 - mean) * inv * gyv.z + byv.z;
                float y3 = (h3 - mean) * inv * gyv.w + byv.w;
                if (YF32) {
                    *(float4*)((float*)yout + (size_t)(row0 + rl) * DD + colbase) = (float4){y0, y1, y2, y3};
                } else {
                    uint2 w; w.x = packbf(y0, y1); w.y = packbf(y2, y3);
                    *(uint2*)((unsigned short*)yout + (size_t)(row0 + rl) * DD + colbase) = w;
                }
            }
        }
    }

    // ---- stage 3 (tokenize only): second LN over h -> y ----
    if (LNH) {
        __syncthreads();
        #pragma unroll
        for (int i = 0; i < 2; ++i) {
            #pragma unroll
            for (int r = 0; r < 4; ++r) {
                const int rl = i * 16 + quad * 4 + r;
                float2 p0 = part[1][rl][0], p1 = part[1][rl][1], p2 = part[1][rl][2], p3 = part[1][rl][3];
                float mean = (p0.x + p1.x + p2.x + p3.x) * (1.f / 256.f);
                float var  = (p0.y + p1.y + p2.y + p3.y) * (1.f / 256.f) - mean * mean;
                float inv  = rsqrtf(var + 1e-5f);
                float y0 = (acc[i][0][r] - mean) * inv * gyv.x + byv.x;
                float y1 = (acc[i][1][r] - mean) * inv * gyv.y + byv.y;
                float y2 = (acc[i][2][r] - mean) * inv * gyv.z + byv.z;
                float y3 = (acc[i][3][r] - mean) * inv * gyv.w + byv.w;
                uint2 w; w.x = packbf(y0, y1); w.y = packbf(y2, y3);
                *(uint2*)((unsigned short*)yout + (size_t)(row0 + rl) * DD + colbase) = w;
            }
        }
    }
}

// ---------------- fused attention: swapped QK^T (P in registers), 64 q/wave, SPLIT-K ----------------
// r15 plateau: ~10-12us issue work vs 34us wall at only 2 waves/SIMD; register prefetch
// deeper than 2 spills (r14). So double TLP instead: the two waves of a block split the
// 1024-key loop (wave0: keys 0-511, wave1: 512-1023) for the SAME (head, q-tile); partial
// o/lsum combine exactly (softmax denom is a pure sum) via one 9.5KB LDS exchange+barrier.
// 2048 blocks x 2 waves = 4096 waves = ~4 waves/SIMD. Per-wave VGPR state unchanged.
__global__ __launch_bounds__(128, 2) void attn_kernel(
    const unsigned short* __restrict__ qr, const unsigned short* __restrict__ kr,
    const unsigned short* __restrict__ vt, unsigned short* __restrict__ ob)
{
    __shared__ float comb[64][37];         // 36 floats/lane, stride 37 (9.5 KB)
    int t = threadIdx.x;
    int lane = t & 63, wave = t >> 6;
    int quad = (lane >> 4), l16 = lane & 15;
    int bid = blockIdx.x;                  // 2048 blocks
    int xcd = bid & 7, jb = bid >> 3;      // jb in [0,256)
    int bh = xcd * 16 + (jb >> 4);         // 16 heads per XCD (both waves: same head)
    int q0 = (jb & 15) * 64;               // 16 q-tiles of 64 per head (both waves: same tile)
    int b = bh >> 3, h = bh & 7;
    const int kbeg = wave * 512;           // wave 0: keys 0-511, wave 1: 512-1023
    const unsigned short* qbase = qr + ((size_t)bh * SS + q0) * DHH;
    const unsigned short* kbase = kr + (size_t)bh * SS * DHH;
    const unsigned short* vbase = vt + (size_t)bh * DHH * SS;
    bf16x8 qa[4];
    #pragma unroll
    for (int qt = 0; qt < 4; ++qt)
        qa[qt] = *(const bf16x8*)(qbase + (size_t)(qt * 16 + l16) * DHH + quad * 8);
    f32x4 o[4][2] = {};
    f32x2 lsum[4] = {};

    bf16x8 kbA[2][2], vbA[2][2], kbB[2][2], vbB[2][2];

    auto loadKV = [&](int k0, bf16x8 (&kb)[2][2], bf16x8 (&vb)[2][2]) {
        #pragma unroll
        for (int kc = 0; kc < 2; ++kc) {
            const unsigned short* kp = kbase + (size_t)(k0 + kc * 32) * DHH;
            kb[kc][0] = *(const bf16x8*)(kp + (size_t)l16 * DHH + quad * 8);        // even keys
            kb[kc][1] = *(const bf16x8*)(kp + (size_t)(16 + l16) * DHH + quad * 8); // odd keys
            vb[kc][0] = *(const bf16x8*)(vbase + (size_t)l16 * SS + k0 + kc * 32 + quad * 8);
            vb[kc][1] = *(const bf16x8*)(vbase + (size_t)(l16 + 16) * SS + k0 + kc * 32 + quad * 8);
        }
    };

    auto tile = [&](bf16x8 (&kb)[2][2], bf16x8 (&vb)[2][2]) {
        __builtin_amdgcn_s_setprio(1);
        #pragma unroll
        for (int qt = 0; qt < 4; ++qt)
            #pragma unroll
            for (int kc = 0; kc < 2; ++kc) {
                f32x4 z = {0.f, 0.f, 0.f, 0.f};
                f32x4 s0 = __builtin_amdgcn_mfma_f32_16x16x32_bf16(kb[kc][0], qa[qt], z, 0, 0, 0);
                f32x4 s1 = __builtin_amdgcn_mfma_f32_16x16x32_bf16(kb[kc][1], qa[qt], z, 0, 0, 0);
                u32x4 pw;
                #pragma unroll
                for (int r = 0; r < 4; ++r) {
                    float p0 = __builtin_amdgcn_exp2f(s0[r]);
                    float p1 = __builtin_amdgcn_exp2f(s1[r]);
                    lsum[qt] += (f32x2){p0, p1};
                    pw[r] = packbf_perm(p0, p1);
                }
                bf16x8 pa = __builtin_bit_cast(bf16x8, pw);
                o[qt][0] = __builtin_amdgcn_mfma_f32_16x16x32_bf16(pa, vb[kc][0], o[qt][0], 0, 0, 0);
                o[qt][1] = __builtin_amdgcn_mfma_f32_16x16x32_bf16(pa, vb[kc][1], o[qt][1], 0, 0, 0);
            }
        __builtin_amdgcn_s_setprio(0);
    };

    loadKV(kbeg, kbA, vbA);
    for (int k0 = kbeg; k0 < kbeg + 512; k0 += 128) {
        loadKV(k0 + 64, kbB, vbB);
        tile(kbA, vbA);
        if (k0 + 128 < kbeg + 512) loadKV(k0 + 128, kbA, vbA);
        tile(kbB, vbB);
    }

    // ---- split-K combine: wave 1 -> LDS, wave 0 adds + finishes ----
    if (wave == 1) {
        #pragma unroll
        for (int qt = 0; qt < 4; ++qt) {
            #pragma unroll
            for (int j = 0; j < 2; ++j)
                #pragma unroll
                for (int r = 0; r < 4; ++r)
                    comb[lane][qt * 8 + j * 4 + r] = o[qt][j][r];
            comb[lane][32 + qt] = lsum[qt][0] + lsum[qt][1];
        }
    }
    __syncthreads();
    if (wave == 0) {
        #pragma unroll
        for (int qt = 0; qt < 4; ++qt) {
            #pragma unroll
            for (int j = 0; j < 2; ++j)
                #pragma unroll
                for (int r = 0; r < 4; ++r)
                    o[qt][j][r] += comb[lane][qt * 8 + j * 4 + r];
            float s = lsum[qt][0] + lsum[qt][1] + comb[lane][32 + qt];
            s += __shfl_xor(s, 16);
            s += __shfl_xor(s, 32);
            float inv = 1.f / s;   // denominator for q = q0 + qt*16 + l16 (replicated over quads)
            #pragma unroll
            for (int r = 0; r < 4; ++r) {
                float invr = __shfl(inv, quad * 4 + r);   // fetch denom for q-row quad*4+r
                int qrow = q0 + qt * 16 + quad * 4 + r;
                size_t base = ((size_t)b * SS + qrow) * DD + h * DHH;
                ob[base + l16]      = f2bf(o[qt][0][r] * invr);
                ob[base + 16 + l16] = f2bf(o[qt][1][r] * invr);
            }
        }
    }
}

extern "C" void kernel_launch(void* const* d_in, const int* in_sizes, int n_in,
                              void* d_out, int out_size, void* d_ws, size_t ws_size,
                              hipStream_t stream)
{
    const float* x        = (const float*)d_in[0];
    const float* tok_w    = (const float*)d_in[1];
    const float* tok_b    = (const float*)d_in[2];
    const float* tnorm_g  = (const float*)d_in[3];
    const float* tnorm_b  = (const float*)d_in[4];
    const float* in_proj_w= (const float*)d_in[5];
    const float* in_proj_b= (const float*)d_in[6];
    const float* out_w    = (const float*)d_in[7];
    const float* out_b    = (const float*)d_in[8];
    const float* ln1_g    = (const float*)d_in[9];
    const float* ln1_b    = (const float*)d_in[10];
    const float* ln2_g    = (const float*)d_in[11];
    const float* ln2_b    = (const float*)d_in[12];
    const float* lin1_w   = (const float*)d_in[13];
    const float* lin1_b   = (const float*)d_in[14];
    const float* lin2_w   = (const float*)d_in[15];
    const float* lin2_b   = (const float*)d_in[16];
    const float* fnorm_g  = (const float*)d_in[17];
    const float* fnorm_b  = (const float*)d_in[18];

    char* ws = (char*)d_ws;
    unsigned short* wb        = (unsigned short*)ws;
    unsigned short* wb_tok    = wb;
    unsigned short* wb_inproj = wb + 131072;
    unsigned short* wb_out    = wb + 917504;
    unsigned short* wb_lin1   = wb + 1179648;
    unsigned short* wb_lin2   = wb + 2228224;
    unsigned short* xb   = (unsigned short*)(ws + 6553600);
    float*          h    = (float*)(ws + 31719424);
    unsigned short* y    = (unsigned short*)(ws + 48496640);
    unsigned short* qr   = (unsigned short*)(ws + 56885248);
    unsigned short* kr   = (unsigned short*)(ws + 65273856);
    unsigned short* vt   = (unsigned short*)(ws + 73662464);
    unsigned short* ob   = (unsigned short*)(ws + 82051072);
    unsigned short* a1   = (unsigned short*)(ws + 90439680);

    convert_weights<<<dim3(12800), dim3(256), 0, stream>>>(tok_w, in_proj_w, out_w, lin1_w, lin2_w, wb);
    convert_x<<<dim3(8192), dim3(256), 0, stream>>>((const float4*)x, (ushort4*)xb, MROWS * TT / 4);

    // tokenize: o = x @ tok_w^T + tok_b ; h = LN_tnorm(o) ; y = LN_ln1[0](h)
    gemm_row<0, 1, 0><<<dim3(MROWS / 32), dim3(256), 0, stream>>>(
        xb, wb_tok, tok_b, nullptr, h, y, tnorm_g, tnorm_b, ln1_g, ln1_b, TT);

    for (int i = 0; i < LL; ++i) {
        // qkv projection + fused RoPE/layout (writes qr, kr, vt directly)
        gemm_qkv<<<dim3(6, MROWS / 128), dim3(256), 0, stream>>>(
            y, wb_inproj + (size_t)i * 3 * DD * DD, in_proj_b + i * 3 * DD, qr, kr, vt);
        attn_kernel<<<dim3(2048), dim3(128), 0, stream>>>(qr, kr, vt, ob);
        // out-proj: h += ob @ out_w^T + out_b ; y = LN_ln2[i](h)
        gemm_row<1, 0, 0><<<dim3(MROWS / 32), dim3(256), 0, stream>>>(
            ob, wb_out + (size_t)i * DD * DD, out_b + i * DD, h, h, y,
            nullptr, nullptr, ln2_g + i * DD, ln2_b + i * DD, DD);
        gemm_lds<256, 1><<<dim3(FFN / 256, MROWS / 128), dim3(256), 0, stream>>>(
            y, wb_lin1 + (size_t)i * FFN * DD, lin1_b + i * FFN, a1, MROWS, FFN, DD);
        if (i < LL - 1) {
            // lin2: h += a1 @ lin2_w^T + lin2_b ; y = LN_ln1[i+1](h)
            gemm_row<1, 0, 0><<<dim3(MROWS / 32), dim3(256), 0, stream>>>(
                a1, wb_lin2 + (size_t)i * DD * FFN, lin2_b + i * DD, h, h, y,
                nullptr, nullptr, ln1_g + (i + 1) * DD, ln1_b + (i + 1) * DD, FFN);
        } else {
            // final: d_out = LN_fnorm(h + a1 @ lin2_w^T + lin2_b), fp32
            gemm_row<1, 0, 1><<<dim3(MROWS / 32), dim3(256), 0, stream>>>(
                a1, wb_lin2 + (size_t)i * DD * FFN, lin2_b + i * DD, h, h, d_out,
                nullptr, nullptr, fnorm_g, fnorm_b, FFN);
        }
    }
}

// Round 19
// 545.408 us; speedup vs baseline: 1.0280x; 1.0280x over previous
//
#include <hip/hip_runtime.h>

#define BB 16
#define SS 1024
#define TT 512
#define DD 256
#define HH 8
#define LL 4
#define FFN 1024
#define DHH 32
#define MROWS (BB*SS)   // 16384

typedef short bf16x8 __attribute__((ext_vector_type(8)));
typedef float f32x4 __attribute__((ext_vector_type(4)));
typedef float f32x2 __attribute__((ext_vector_type(2)));
typedef unsigned int u32x4 __attribute__((ext_vector_type(4)));

__device__ __forceinline__ unsigned short f2bf(float f) {
    unsigned int u = __float_as_uint(f);
    unsigned int r = (u + 0x7fffu + ((u >> 16) & 1u)) >> 16;
    return (unsigned short)r;
}
__device__ __forceinline__ float bf2f(unsigned short h) {
    return __uint_as_float(((unsigned int)h) << 16);
}
__device__ __forceinline__ unsigned int packbf(float a, float b) {
    return (__float_as_uint(a) >> 16) | (__float_as_uint(b) & 0xffff0000u);
}
// one v_perm_b32: low16 = bf16trunc(p0), high16 = bf16trunc(p1)
__device__ __forceinline__ unsigned int packbf_perm(float p0, float p1) {
    return __builtin_amdgcn_perm(__float_as_uint(p1), __float_as_uint(p0), 0x07060302u);
}

// async global->LDS, 16B per lane. LDS dest must be wave-uniform base + lane*16.
__device__ __forceinline__ void g2l16(const unsigned short* g, unsigned short* l) {
    __builtin_amdgcn_global_load_lds(
        (const __attribute__((address_space(1))) unsigned int*)g,
        (__attribute__((address_space(3))) unsigned int*)l, 16, 0, 0);
}

// ---------------- weight conversion (fp32 -> bf16) ----------------
__global__ __launch_bounds__(256) void convert_weights(
    const float* __restrict__ w0, const float* __restrict__ w1, const float* __restrict__ w2,
    const float* __restrict__ w3, const float* __restrict__ w4, unsigned short* __restrict__ dst)
{
    int i = blockIdx.x * 256 + threadIdx.x;
    if (i >= 3276800) return;
    float v;
    if (i < 131072)        v = w0[i];
    else if (i < 917504)   v = w1[i - 131072];
    else if (i < 1179648)  v = w2[i - 917504];
    else if (i < 2228224)  v = w3[i - 1179648];
    else                   v = w4[i - 2228224];
    dst[i] = f2bf(v);
}

__global__ __launch_bounds__(256) void convert_x(const float4* __restrict__ x, ushort4* __restrict__ xb, int n4)
{
    int i = blockIdx.x * 256 + threadIdx.x;
    if (i >= n4) return;
    float4 v = x[i];
    ushort4 o;
    o.x = f2bf(v.x); o.y = f2bf(v.y); o.z = f2bf(v.z); o.w = f2bf(v.w);
    xb[i] = o;
}

// ---------------- wide GEMM (lin1): 128 x BN block, BK=32, permuted-B wide epilogue ----------------
template<int BN, int RELU>
__global__ __launch_bounds__(256, 2) void gemm_lds(
    const unsigned short* __restrict__ A, const unsigned short* __restrict__ Bw,
    const float* __restrict__ bias, void* out, int M, int N, int K)
{
    constexpr int NJ = BN / 32;
    __shared__ __align__(16) unsigned short sA[2][128 * 32];
    __shared__ __align__(16) unsigned short sB[2][BN * 32];
    const int t = threadIdx.x;
    const int lane = t & 63, quad = lane >> 4, l16 = lane & 15;
    const int wave = t >> 6, wm = wave >> 1, wn = wave & 1;
    const int row0 = blockIdx.y * 128, col0 = blockIdx.x * BN;

    const unsigned short* gA = A + (size_t)(row0 + (t >> 2)) * K + (t & 3) * 8;
    const size_t rstep = (size_t)64 * K;
    const unsigned short* gBp[BN / 64];
    #pragma unroll
    for (int p = 0; p < BN / 64; ++p) {
        int l = p * 64 + (t >> 2);
        int wrow = (l & (16 * NJ)) + (l & 15) * NJ + ((l >> 4) & (NJ - 1));
        gBp[p] = Bw + (size_t)(col0 + wrow) * K + (t & 3) * 8;
    }

    f32x4 acc[4][NJ];
    #pragma unroll
    for (int i = 0; i < 4; ++i)
        #pragma unroll
        for (int j = 0; j < NJ; ++j)
            acc[i][j] = (f32x4){0.f, 0.f, 0.f, 0.f};

    g2l16(gA, &sA[0][t * 8]);
    g2l16(gA + rstep, &sA[0][(t + 256) * 8]);
    #pragma unroll
    for (int p = 0; p < BN / 64; ++p)
        g2l16(gBp[p], &sB[0][p * 2048 + t * 8]);

    for (int k0 = 0; k0 < K; k0 += 32) {
        const int cur = (k0 >> 5) & 1;
        __syncthreads();
        if (k0 + 32 < K) {
            const int nxt = cur ^ 1;
            g2l16(gA + k0 + 32, &sA[nxt][t * 8]);
            g2l16(gA + rstep + k0 + 32, &sA[nxt][(t + 256) * 8]);
            #pragma unroll
            for (int p = 0; p < BN / 64; ++p)
                g2l16(gBp[p] + k0 + 32, &sB[nxt][p * 2048 + t * 8]);
        }
        bf16x8 a[4], b[NJ];
        #pragma unroll
        for (int i = 0; i < 4; ++i)
            a[i] = *(const bf16x8*)(&sA[cur][(wm * 64 + i * 16 + l16) * 32 + quad * 8]);
        #pragma unroll
        for (int j = 0; j < NJ; ++j)
            b[j] = *(const bf16x8*)(&sB[cur][(wn * (BN / 2) + j * 16 + l16) * 32 + quad * 8]);
        #pragma unroll
        for (int i = 0; i < 4; ++i)
            #pragma unroll
            for (int j = 0; j < NJ; ++j)
                acc[i][j] = __builtin_amdgcn_mfma_f32_16x16x32_bf16(a[i], b[j], acc[i][j], 0, 0, 0);
    }

    const int colbase = col0 + wn * (BN / 2) + l16 * NJ;
    float bb[NJ];
    #pragma unroll
    for (int j = 0; j < NJ; ++j) bb[j] = bias[colbase + j];
    #pragma unroll
    for (int i = 0; i < 4; ++i) {
        #pragma unroll
        for (int r = 0; r < 4; ++r) {
            int row = row0 + wm * 64 + i * 16 + quad * 4 + r;
            float v[NJ];
            #pragma unroll
            for (int j = 0; j < NJ; ++j) {
                v[j] = acc[i][j][r] + bb[j];
                if (RELU) v[j] = fmaxf(v[j], 0.f);
            }
            unsigned short* dst = (unsigned short*)out + (size_t)row * N + colbase;
            if constexpr (NJ == 4) {
                uint2 w; w.x = packbf(v[0], v[1]); w.y = packbf(v[2], v[3]);
                *(uint2*)dst = w;
            } else {
                uint4 w; w.x = packbf(v[0], v[1]); w.y = packbf(v[2], v[3]);
                w.z = packbf(v[4], v[5]); w.w = packbf(v[6], v[7]);
                *(uint4*)dst = w;
            }
        }
    }
}

// ---------------- qkv GEMM with fused RoPE + layout epilogue ----------------
// (writes qr/kr/vt directly, no rope dispatch)
__global__ __launch_bounds__(256, 2) void gemm_qkv(
    const unsigned short* __restrict__ A, const unsigned short* __restrict__ Bw,
    const float* __restrict__ bias,
    unsigned short* __restrict__ qr, unsigned short* __restrict__ kr,
    unsigned short* __restrict__ vt)
{
    constexpr int K = 256;
    __shared__ __align__(16) unsigned short sA[2][128 * 32];   // 16 KB
    __shared__ __align__(16) unsigned short sB[2][128 * 32];   // 16 KB
    __shared__ float scc[128 * 20], scs[128 * 20];             // 20 KB sincos (stride-20 pad)
    const int t = threadIdx.x;
    const int lane = t & 63, quad = lane >> 4, l16 = lane & 15;
    const int wave = t >> 6, wm = wave >> 1, wn = wave & 1;
    const int row0 = blockIdx.y * 128, col0 = blockIdx.x * 128;
    const int sec = blockIdx.x >> 1;                           // 0=Q 1=K 2=V
    const int b = row0 >> 10, s0 = row0 & 1023;

    if (sec < 2) {
        #pragma unroll
        for (int k = 0; k < 8; ++k) {
            int e = t * 8 + k;                                 // 2048 entries
            int rl = e >> 4, jj = e & 15;
            float ivf = __expf(-(float)jj * 0.575646273248511f);  // 10000^(-jj/16)
            float c, sn;
            __sincosf((float)(s0 + rl) * ivf, &sn, &c);
            scc[rl * 20 + jj] = c;
            scs[rl * 20 + jj] = sn;
        }
    }

    const unsigned short* gA = A + (size_t)(row0 + (t >> 2)) * K + (t & 3) * 8;
    const size_t rstep = (size_t)64 * K;
    const unsigned short* gBp[2];
    #pragma unroll
    for (int p = 0; p < 2; ++p) {
        int l = p * 64 + (t >> 2);
        int wrow = (l & 64) + (l & 15) * 4 + ((l >> 4) & 3);
        gBp[p] = Bw + (size_t)(col0 + wrow) * K + (t & 3) * 8;
    }

    f32x4 acc[4][4];
    #pragma unroll
    for (int i = 0; i < 4; ++i)
        #pragma unroll
        for (int j = 0; j < 4; ++j)
            acc[i][j] = (f32x4){0.f, 0.f, 0.f, 0.f};

    g2l16(gA, &sA[0][t * 8]);
    g2l16(gA + rstep, &sA[0][(t + 256) * 8]);
    #pragma unroll
    for (int p = 0; p < 2; ++p)
        g2l16(gBp[p], &sB[0][p * 2048 + t * 8]);

    for (int k0 = 0; k0 < K; k0 += 32) {
        const int cur = (k0 >> 5) & 1;
        __syncthreads();
        if (k0 + 32 < K) {
            const int nxt = cur ^ 1;
            g2l16(gA + k0 + 32, &sA[nxt][t * 8]);
            g2l16(gA + rstep + k0 + 32, &sA[nxt][(t + 256) * 8]);
            #pragma unroll
            for (int p = 0; p < 2; ++p)
                g2l16(gBp[p] + k0 + 32, &sB[nxt][p * 2048 + t * 8]);
        }
        bf16x8 a[4], bfr[4];
        #pragma unroll
        for (int i = 0; i < 4; ++i)
            a[i] = *(const bf16x8*)(&sA[cur][(wm * 64 + i * 16 + l16) * 32 + quad * 8]);
        #pragma unroll
        for (int j = 0; j < 4; ++j)
            bfr[j] = *(const bf16x8*)(&sB[cur][(wn * 64 + j * 16 + l16) * 32 + quad * 8]);
        #pragma unroll
        for (int i = 0; i < 4; ++i)
            #pragma unroll
            for (int j = 0; j < 4; ++j)
                acc[i][j] = __builtin_amdgcn_mfma_f32_16x16x32_bf16(a[i], bfr[j], acc[i][j], 0, 0, 0);
    }

    // ---- fused RoPE/layout epilogue ----
    const int gcol = col0 + wn * 64 + l16 * 4;     // global qkv column
    const int cc = gcol & 255;                     // column within section
    const int h = cc >> 5, d0v = cc & 31, j0 = d0v & 15;
    const int bh = (b << 3) | h;
    float bbv[4];
    *(float4*)bbv = *(const float4*)(bias + gcol);

    if (sec < 2) {
        const float sgn = ((l16 & 4) == 0) ? -1.f : 1.f;   // d<16 -> -partner
        const float qs = 1.4426950408889634f / 5.656854249492381f;  // log2e/sqrt(32)
        #pragma unroll
        for (int i = 0; i < 4; ++i) {
            #pragma unroll
            for (int r = 0; r < 4; ++r) {
                const int rl = wm * 64 + i * 16 + quad * 4 + r;
                float v0 = acc[i][0][r] + bbv[0];
                float v1 = acc[i][1][r] + bbv[1];
                float v2 = acc[i][2][r] + bbv[2];
                float v3 = acc[i][3][r] + bbv[3];
                float p0 = __shfl_xor(v0, 4);
                float p1 = __shfl_xor(v1, 4);
                float p2 = __shfl_xor(v2, 4);
                float p3 = __shfl_xor(v3, 4);
                float4 cv = *(const float4*)(&scc[rl * 20 + j0]);
                float4 sv = *(const float4*)(&scs[rl * 20 + j0]);
                float o0 = v0 * cv.x + sgn * p0 * sv.x;
                float o1 = v1 * cv.y + sgn * p1 * sv.y;
                float o2 = v2 * cv.z + sgn * p2 * sv.z;
                float o3 = v3 * cv.w + sgn * p3 * sv.w;
                const int s = s0 + rl;
                uint2 w;
                if (sec == 0) {
                    o0 *= qs; o1 *= qs; o2 *= qs; o3 *= qs;
                    w.x = packbf(o0, o1); w.y = packbf(o2, o3);
                    *(uint2*)(qr + ((size_t)bh * SS + s) * DHH + d0v) = w;
                } else {
                    int jj2 = s & 31;
                    int sp = (s & ~31) | (((jj2 & 1) << 4) | (jj2 >> 1));  // even/odd interleave
                    w.x = packbf(o0, o1); w.y = packbf(o2, o3);
                    *(uint2*)(kr + ((size_t)bh * SS + sp) * DHH + d0v) = w;
                }
            }
        }
    } else {
        #pragma unroll
        for (int i = 0; i < 4; ++i) {
            const int sbase = s0 + wm * 64 + i * 16 + quad * 4;
            #pragma unroll
            for (int j = 0; j < 4; ++j) {
                float w0 = acc[i][j][0] + bbv[j];
                float w1 = acc[i][j][1] + bbv[j];
                float w2 = acc[i][j][2] + bbv[j];
                float w3 = acc[i][j][3] + bbv[j];
                uint2 w; w.x = packbf(w0, w1); w.y = packbf(w2, w3);
                *(uint2*)(vt + ((size_t)bh * DHH + d0v + j) * SS + sbase) = w;
            }
        }
    }
}

// ---------------- full-row GEMM (tokenize / out-proj / lin2): 32 x 256 block,
// BK=64 via QUARTER-PAIR staging (kept: measured ~25us aggregate gain r14/r15).
// One barrier per 64-K; conflict-free 32-half-row LDS layout. Fused bias+resid+row-LN.
template<int RESID, int LNH, int YF32>
__global__ __launch_bounds__(256, 2) void gemm_row(
    const unsigned short* __restrict__ A, const unsigned short* __restrict__ Bw,
    const float* __restrict__ bias, const float* __restrict__ resid,
    float* __restrict__ hout, void* __restrict__ yout,
    const float* __restrict__ gh, const float* __restrict__ bh,
    const float* __restrict__ gy, const float* __restrict__ by, int K)
{
    __shared__ __align__(16) unsigned short sA[4][32 * 32];    //  8 KB (4 k-quarters)
    __shared__ __align__(16) unsigned short sB[4][256 * 32];   // 64 KB
    __shared__ float2 part[2][32][4];                          //  1 KB row partials
    const int t = threadIdx.x;
    const int quad = (t >> 4) & 3, l16 = t & 15;
    const int wn = t >> 6;                                     // 4 col-waves
    const int row0 = blockIdx.x * 32;

    const int tq = t & 127, aq = t >> 7;   // A staging: waves 0-1 -> quarter lo, 2-3 -> hi
    const unsigned short* gA = A + (size_t)(row0 + (tq >> 2)) * K + (tq & 3) * 8;
    const unsigned short* gB[4];
    #pragma unroll
    for (int p = 0; p < 4; ++p) {
        int l = p * 64 + (t >> 2);
        gB[p] = Bw + (size_t)((l & 192) + (l & 15) * 4 + ((l >> 4) & 3)) * K + (t & 3) * 8;
    }

    f32x4 acc[2][4];
    #pragma unroll
    for (int i = 0; i < 2; ++i)
        #pragma unroll
        for (int j = 0; j < 4; ++j)
            acc[i][j] = (f32x4){0.f, 0.f, 0.f, 0.f};

    // stage a PAIR of 32-k quarters (64 K) into quarters 2p / 2p+1
    auto stage = [&](int k0, int p) {
        g2l16(gA + k0 + aq * 32, &sA[2 * p + aq][tq * 8]);
        #pragma unroll
        for (int i = 0; i < 4; ++i) {
            g2l16(gB[i] + k0,      &sB[2 * p][i * 2048 + t * 8]);
            g2l16(gB[i] + k0 + 32, &sB[2 * p + 1][i * 2048 + t * 8]);
        }
    };

    stage(0, 0);
    for (int k0 = 0; k0 < K; k0 += 64) {
        const int cur = (k0 >> 6) & 1;
        __syncthreads();
        if (k0 + 64 < K) stage(k0 + 64, cur ^ 1);
        #pragma unroll
        for (int kh = 0; kh < 2; ++kh) {
            bf16x8 a[2], b[4];
            #pragma unroll
            for (int i = 0; i < 2; ++i)
                a[i] = *(const bf16x8*)(&sA[2 * cur + kh][(i * 16 + l16) * 32 + quad * 8]);
            #pragma unroll
            for (int j = 0; j < 4; ++j)
                b[j] = *(const bf16x8*)(&sB[2 * cur + kh][(wn * 64 + j * 16 + l16) * 32 + quad * 8]);
            #pragma unroll
            for (int i = 0; i < 2; ++i)
                #pragma unroll
                for (int j = 0; j < 4; ++j)
                    acc[i][j] = __builtin_amdgcn_mfma_f32_16x16x32_bf16(a[i], b[j], acc[i][j], 0, 0, 0);
        }
    }

    // ---- epilogue: bias + resid, row stats (stage 1) ----
    const int colbase = wn * 64 + l16 * 4;
    const float4 bb = *(const float4*)(bias + colbase);
    #pragma unroll
    for (int i = 0; i < 2; ++i) {
        #pragma unroll
        for (int r = 0; r < 4; ++r) {
            const int rl = i * 16 + quad * 4 + r;
            float v0 = acc[i][0][r] + bb.x;
            float v1 = acc[i][1][r] + bb.y;
            float v2 = acc[i][2][r] + bb.z;
            float v3 = acc[i][3][r] + bb.w;
            if (RESID) {
                float4 rv = *(const float4*)(resid + (size_t)(row0 + rl) * DD + colbase);
                v0 += rv.x; v1 += rv.y; v2 += rv.z; v3 += rv.w;
            }
            acc[i][0][r] = v0; acc[i][1][r] = v1; acc[i][2][r] = v2; acc[i][3][r] = v3;
            float s = v0 + v1 + v2 + v3;
            float ss = v0 * v0 + v1 * v1 + v2 * v2 + v3 * v3;
            #pragma unroll
            for (int m = 1; m <= 8; m <<= 1) { s += __shfl_xor(s, m); ss += __shfl_xor(ss, m); }
            if (l16 == 0) part[0][rl][wn] = (float2){s, ss};
        }
    }
    __syncthreads();

    float4 gyv = *(const float4*)(gy + colbase);
    float4 byv = *(const float4*)(by + colbase);
    float4 ghv = {0.f, 0.f, 0.f, 0.f}, bhv = {0.f, 0.f, 0.f, 0.f};
    if (LNH) { ghv = *(const float4*)(gh + colbase); bhv = *(const float4*)(bh + colbase); }

    // ---- stage 2: LN from stats; write h; (LNH: restage stats of h) ----
    #pragma unroll
    for (int i = 0; i < 2; ++i) {
        #pragma unroll
        for (int r = 0; r < 4; ++r) {
            const int rl = i * 16 + quad * 4 + r;
            float2 p0 = part[0][rl][0], p1 = part[0][rl][1], p2 = part[0][rl][2], p3 = part[0][rl][3];
            float mean = (p0.x + p1.x + p2.x + p3.x) * (1.f / 256.f);
            float var  = (p0.y + p1.y + p2.y + p3.y) * (1.f / 256.f) - mean * mean;
            float inv  = rsqrtf(var + 1e-5f);
            float h0, h1, h2, h3;
            if (LNH) {
                h0 = (acc[i][0][r] - mean) * inv * ghv.x + bhv.x;
                h1 = (acc[i][1][r] - mean) * inv * ghv.y + bhv.y;
                h2 = (acc[i][2][r] - mean) * inv * ghv.z + bhv.z;
                h3 = (acc[i][3][r] - mean) * inv * ghv.w + bhv.w;
            } else {
                h0 = acc[i][0][r]; h1 = acc[i][1][r]; h2 = acc[i][2][r]; h3 = acc[i][3][r];
            }
            if (!YF32)
                *(float4*)(hout + (size_t)(row0 + rl) * DD + colbase) = (float4){h0, h1, h2, h3};
            if (LNH) {
                acc[i][0][r] = h0; acc[i][1][r] = h1; acc[i][2][r] = h2; acc[i][3][r] = h3;
                float s = h0 + h1 + h2 + h3;
                float ss = h0 * h0 + h1 * h1 + h2 * h2 + h3 * h3;
                #pragma unroll
                for (int m = 1; m <= 8; m <<= 1) { s += __shfl_xor(s, m); ss += __shfl_xor(ss, m); }
                if (l16 == 0) part[1][rl][wn] = (float2){s, ss};
            } else {
                float y0 = (h0 - mean) * inv * gyv.x + byv.x;
                float y1 = (h1 - mean) * inv * gyv.y + byv.y;
                float y2 = (h2 - mean) * inv * gyv.z + byv.z;
                float y3 = (h3 - mean) * inv * gyv.w + byv.w;
                if (YF32) {
                    *(float4*)((float*)yout + (size_t)(row0 + rl) * DD + colbase) = (float4){y0, y1, y2, y3};
                } else {
                    uint2 w; w.x = packbf(y0, y1); w.y = packbf(y2, y3);
                    *(uint2*)((unsigned short*)yout + (size_t)(row0 + rl) * DD + colbase) = w;
                }
            }
        }
    }

    // ---- stage 3 (tokenize only): second LN over h -> y ----
    if (LNH) {
        __syncthreads();
        #pragma unroll
        for (int i = 0; i < 2; ++i) {
            #pragma unroll
            for (int r = 0; r < 4; ++r) {
                const int rl = i * 16 + quad * 4 + r;
                float2 p0 = part[1][rl][0], p1 = part[1][rl][1], p2 = part[1][rl][2], p3 = part[1][rl][3];
                float mean = (p0.x + p1.x + p2.x + p3.x) * (1.f / 256.f);
                float var  = (p0.y + p1.y + p2.y + p3.y) * (1.f / 256.f) - mean * mean;
                float inv  = rsqrtf(var + 1e-5f);
                float y0 = (acc[i][0][r] - mean) * inv * gyv.x + byv.x;
                float y1 = (acc[i][1][r] - mean) * inv * gyv.y + byv.y;
                float y2 = (acc[i][2][r] - mean) * inv * gyv.z + byv.z;
                float y3 = (acc[i][3][r] - mean) * inv * gyv.w + byv.w;
                uint2 w; w.x = packbf(y0, y1); w.y = packbf(y2, y3);
                *(uint2*)((unsigned short*)yout + (size_t)(row0 + rl) * DD + colbase) = w;
            }
        }
    }
}

// ---------------- fused attention: swapped QK^T (P in registers), 64 queries/wave ----------------
// Round-15 measured-best shape (2-deep A/B prefetch, no split-K). r16 split-K regressed
// (combine + wave-1 idle + doubled Q fetch beat the TLP gain) -> attn is in-wave
// chain-bound; ~34us is this formulation's floor. r14 proved register depth >2 spills.
__global__ __launch_bounds__(128, 2) void attn_kernel(
    const unsigned short* __restrict__ qr, const unsigned short* __restrict__ kr,
    const unsigned short* __restrict__ vt, unsigned short* __restrict__ ob)
{
    int t = threadIdx.x;
    int lane = t & 63, wave = t >> 6;
    int quad = (lane >> 4), l16 = lane & 15;
    int bid = blockIdx.x;                  // 1024 blocks
    int xcd = bid & 7, jb = bid >> 3;      // jb in [0,128)
    int gid = jb * 2 + wave;               // [0,256)
    int bh = xcd * 16 + (gid >> 4);        // 16 heads per XCD
    int q0 = (gid & 15) * 64;              // 16 q-tiles of 64 per head
    int b = bh >> 3, h = bh & 7;
    const unsigned short* qbase = qr + ((size_t)bh * SS + q0) * DHH;
    const unsigned short* kbase = kr + (size_t)bh * SS * DHH;
    const unsigned short* vbase = vt + (size_t)bh * DHH * SS;
    bf16x8 qa[4];
    #pragma unroll
    for (int qt = 0; qt < 4; ++qt)
        qa[qt] = *(const bf16x8*)(qbase + (size_t)(qt * 16 + l16) * DHH + quad * 8);
    f32x4 o[4][2] = {};
    f32x2 lsum[4] = {};

    bf16x8 kbA[2][2], vbA[2][2], kbB[2][2], vbB[2][2];

    auto loadKV = [&](int k0, bf16x8 (&kb)[2][2], bf16x8 (&vb)[2][2]) {
        #pragma unroll
        for (int kc = 0; kc < 2; ++kc) {
            const unsigned short* kp = kbase + (size_t)(k0 + kc * 32) * DHH;
            kb[kc][0] = *(const bf16x8*)(kp + (size_t)l16 * DHH + quad * 8);        // even keys
            kb[kc][1] = *(const bf16x8*)(kp + (size_t)(16 + l16) * DHH + quad * 8); // odd keys
            vb[kc][0] = *(const bf16x8*)(vbase + (size_t)l16 * SS + k0 + kc * 32 + quad * 8);
            vb[kc][1] = *(const bf16x8*)(vbase + (size_t)(l16 + 16) * SS + k0 + kc * 32 + quad * 8);
        }
    };

    auto tile = [&](bf16x8 (&kb)[2][2], bf16x8 (&vb)[2][2]) {
        __builtin_amdgcn_s_setprio(1);
        #pragma unroll
        for (int qt = 0; qt < 4; ++qt)
            #pragma unroll
            for (int kc = 0; kc < 2; ++kc) {
                f32x4 z = {0.f, 0.f, 0.f, 0.f};
                f32x4 s0 = __builtin_amdgcn_mfma_f32_16x16x32_bf16(kb[kc][0], qa[qt], z, 0, 0, 0);
                f32x4 s1 = __builtin_amdgcn_mfma_f32_16x16x32_bf16(kb[kc][1], qa[qt], z, 0, 0, 0);
                u32x4 pw;
                #pragma unroll
                for (int r = 0; r < 4; ++r) {
                    float p0 = __builtin_amdgcn_exp2f(s0[r]);
                    float p1 = __builtin_amdgcn_exp2f(s1[r]);
                    lsum[qt] += (f32x2){p0, p1};
                    pw[r] = packbf_perm(p0, p1);
                }
                bf16x8 pa = __builtin_bit_cast(bf16x8, pw);
                o[qt][0] = __builtin_amdgcn_mfma_f32_16x16x32_bf16(pa, vb[kc][0], o[qt][0], 0, 0, 0);
                o[qt][1] = __builtin_amdgcn_mfma_f32_16x16x32_bf16(pa, vb[kc][1], o[qt][1], 0, 0, 0);
            }
        __builtin_amdgcn_s_setprio(0);
    };

    loadKV(0, kbA, vbA);
    for (int k0 = 0; k0 < SS; k0 += 128) {
        loadKV(k0 + 64, kbB, vbB);
        tile(kbA, vbA);
        if (k0 + 128 < SS) loadKV(k0 + 128, kbA, vbA);
        tile(kbB, vbB);
    }

    #pragma unroll
    for (int qt = 0; qt < 4; ++qt) {
        float s = lsum[qt][0] + lsum[qt][1];
        s += __shfl_xor(s, 16);
        s += __shfl_xor(s, 32);
        float inv = 1.f / s;   // denominator for q = q0 + qt*16 + l16 (replicated over quads)
        #pragma unroll
        for (int r = 0; r < 4; ++r) {
            float invr = __shfl(inv, quad * 4 + r);   // fetch denom for q-row quad*4+r
            int qrow = q0 + qt * 16 + quad * 4 + r;
            size_t base = ((size_t)b * SS + qrow) * DD + h * DHH;
            ob[base + l16]      = f2bf(o[qt][0][r] * invr);
            ob[base + 16 + l16] = f2bf(o[qt][1][r] * invr);
        }
    }
}

extern "C" void kernel_launch(void* const* d_in, const int* in_sizes, int n_in,
                              void* d_out, int out_size, void* d_ws, size_t ws_size,
                              hipStream_t stream)
{
    const float* x        = (const float*)d_in[0];
    const float* tok_w    = (const float*)d_in[1];
    const float* tok_b    = (const float*)d_in[2];
    const float* tnorm_g  = (const float*)d_in[3];
    const float* tnorm_b  = (const float*)d_in[4];
    const float* in_proj_w= (const float*)d_in[5];
    const float* in_proj_b= (const float*)d_in[6];
    const float* out_w    = (const float*)d_in[7];
    const float* out_b    = (const float*)d_in[8];
    const float* ln1_g    = (const float*)d_in[9];
    const float* ln1_b    = (const float*)d_in[10];
    const float* ln2_g    = (const float*)d_in[11];
    const float* ln2_b    = (const float*)d_in[12];
    const float* lin1_w   = (const float*)d_in[13];
    const float* lin1_b   = (const float*)d_in[14];
    const float* lin2_w   = (const float*)d_in[15];
    const float* lin2_b   = (const float*)d_in[16];
    const float* fnorm_g  = (const float*)d_in[17];
    const float* fnorm_b  = (const float*)d_in[18];

    char* ws = (char*)d_ws;
    unsigned short* wb        = (unsigned short*)ws;
    unsigned short* wb_tok    = wb;
    unsigned short* wb_inproj = wb + 131072;
    unsigned short* wb_out    = wb + 917504;
    unsigned short* wb_lin1   = wb + 1179648;
    unsigned short* wb_lin2   = wb + 2228224;
    unsigned short* xb   = (unsigned short*)(ws + 6553600);
    float*          h    = (float*)(ws + 31719424);
    unsigned short* y    = (unsigned short*)(ws + 48496640);
    unsigned short* qr   = (unsigned short*)(ws + 56885248);
    unsigned short* kr   = (unsigned short*)(ws + 65273856);
    unsigned short* vt   = (unsigned short*)(ws + 73662464);
    unsigned short* ob   = (unsigned short*)(ws + 82051072);
    unsigned short* a1   = (unsigned short*)(ws + 90439680);

    convert_weights<<<dim3(12800), dim3(256), 0, stream>>>(tok_w, in_proj_w, out_w, lin1_w, lin2_w, wb);
    convert_x<<<dim3(8192), dim3(256), 0, stream>>>((const float4*)x, (ushort4*)xb, MROWS * TT / 4);

    // tokenize: o = x @ tok_w^T + tok_b ; h = LN_tnorm(o) ; y = LN_ln1[0](h)
    gemm_row<0, 1, 0><<<dim3(MROWS / 32), dim3(256), 0, stream>>>(
        xb, wb_tok, tok_b, nullptr, h, y, tnorm_g, tnorm_b, ln1_g, ln1_b, TT);

    for (int i = 0; i < LL; ++i) {
        // qkv projection + fused RoPE/layout (writes qr, kr, vt directly)
        gemm_qkv<<<dim3(6, MROWS / 128), dim3(256), 0, stream>>>(
            y, wb_inproj + (size_t)i * 3 * DD * DD, in_proj_b + i * 3 * DD, qr, kr, vt);
        attn_kernel<<<dim3(1024), dim3(128), 0, stream>>>(qr, kr, vt, ob);
        // out-proj: h += ob @ out_w^T + out_b ; y = LN_ln2[i](h)
        gemm_row<1, 0, 0><<<dim3(MROWS / 32), dim3(256), 0, stream>>>(
            ob, wb_out + (size_t)i * DD * DD, out_b + i * DD, h, h, y,
            nullptr, nullptr, ln2_g + i * DD, ln2_b + i * DD, DD);
        gemm_lds<256, 1><<<dim3(FFN / 256, MROWS / 128), dim3(256), 0, stream>>>(
            y, wb_lin1 + (size_t)i * FFN * DD, lin1_b + i * FFN, a1, MROWS, FFN, DD);
        if (i < LL - 1) {
            // lin2: h += a1 @ lin2_w^T + lin2_b ; y = LN_ln1[i+1](h)
            gemm_row<1, 0, 0><<<dim3(MROWS / 32), dim3(256), 0, stream>>>(
                a1, wb_lin2 + (size_t)i * DD * FFN, lin2_b + i * DD, h, h, y,
                nullptr, nullptr, ln1_g + (i + 1) * DD, ln1_b + (i + 1) * DD, FFN);
        } else {
            // final: d_out = LN_fnorm(h + a1 @ lin2_w^T + lin2_b), fp32
            gemm_row<1, 0, 1><<<dim3(MROWS / 32), dim3(256), 0, stream>>>(
                a1, wb_lin2 + (size_t)i * DD * FFN, lin2_b + i * DD, h, h, d_out,
                nullptr, nullptr, fnorm_g, fnorm_b, FFN);
        }
    }
}